// Round 10
// baseline (4050.139 us; speedup 1.0000x reference)
//
#include <hip/hip_runtime.h>
#include <stdint.h>
#include <type_traits>

#define NE 8
#define NH 128
#define ND 8
#define NCONT 168
#define NHOR 24
#define NB 4096
#define NG 512   // 4*NH
#define BT 64    // batch rows per block

// gate input scales folded into weights: i,f,o -> -log2(e); g -> +2*log2(e)
#define S_SIG (-1.44269504088896f)
#define S_TANH (2.88539008177793f)

typedef float f32x4 __attribute__((ext_vector_type(4)));
typedef float f32x2 __attribute__((ext_vector_type(2)));
typedef short bf16x8 __attribute__((ext_vector_type(8)));
typedef unsigned int u32x2 __attribute__((ext_vector_type(2)));

template <int N> using ic = std::integral_constant<int, N>;

__device__ __forceinline__ unsigned short f2bf(float f){
  union { float f; unsigned u; } v; v.f = f;
  unsigned r = (v.u + 0x7FFFu + ((v.u >> 16) & 1u)) >> 16;
  return (unsigned short)r;
}
__device__ __forceinline__ unsigned cvt_pk_bf16(float lo, float hi){
  unsigned r;
  asm("v_cvt_pk_bf16_f32 %0, %1, %2" : "=v"(r) : "v"(lo), "v"(hi));
  return r;
}

__device__ __forceinline__ f32x2 splat2(float v){ f32x2 r; r.x = v; r.y = v; return r; }
__device__ __forceinline__ f32x2 lo2(f32x4 v){ return __builtin_shufflevector(v, v, 0, 1); }
__device__ __forceinline__ f32x2 hi2(f32x4 v){ return __builtin_shufflevector(v, v, 2, 3); }
__device__ __forceinline__ f32x2 fma2(f32x2 a, f32x2 b, f32x2 c){
  return __builtin_elementwise_fma(a, b, c);
}
__device__ __forceinline__ f32x2 exp2_2(f32x2 x){
  f32x2 o; o.x = __builtin_amdgcn_exp2f(x.x); o.y = __builtin_amdgcn_exp2f(x.y); return o;
}
__device__ __forceinline__ f32x2 rcp2(f32x2 x){
  f32x2 o; o.x = __builtin_amdgcn_rcpf(x.x); o.y = __builtin_amdgcn_rcpf(x.y); return o;
}
// with z pre-scaled by -log2e: sigmoid = rcp(1 + exp2(z_s))
// with z pre-scaled by +2log2e: r = rcp(1+exp2(z_s)); tanh = 1 - 2r
__device__ __forceinline__ f32x2 gate2(f32x2 zs){
  return rcp2(exp2_2(zs) + splat2(1.0f));
}

__global__ void prep_fxw_enc(const float* __restrict__ feats, const float* __restrict__ W,
                             const float* __restrict__ bias, float* __restrict__ out){
  int idx = blockIdx.x * blockDim.x + threadIdx.x;
  if (idx >= NE * NCONT * NG) return;
  int j = idx & (NG - 1);
  int t = (idx >> 9) % NCONT;
  int e = idx / (NCONT * NG);
  float s = bias[e * NG + j];
  #pragma unroll
  for (int i = 0; i < ND; ++i)
    s += feats[t * ND + i] * W[(e * 9 + 1 + i) * NG + j];
  float sc = ((j >> 7) == 2) ? S_TANH : S_SIG;
  out[idx] = s * sc;
}

__global__ void prep_fxw_dec(const float* __restrict__ feats, const float* __restrict__ W,
                             const float* __restrict__ bias, float* __restrict__ out){
  int idx = blockIdx.x * blockDim.x + threadIdx.x;
  if (idx >= NE * NHOR * NG) return;
  int j = idx & (NG - 1);
  int t = (idx >> 9) % NHOR;
  int e = idx / (NHOR * NG);
  float s = bias[e * NG + j];
  #pragma unroll
  for (int i = 0; i < ND; ++i)
    s += feats[(NCONT + t) * ND + i] * W[(e * ND + i) * NG + j];
  float sc = ((j >> 7) == 2) ? S_TANH : S_SIG;
  out[idx] = s * sc;
}

__global__ void prep_node(const int* __restrict__ nid, const float* __restrict__ emb,
                          float* __restrict__ node_w){
  int b = blockIdx.x * blockDim.x + threadIdx.x;
  if (b >= NB) return;
  int n = nid[b];
  float a[NE]; float s = 0.f;
  #pragma unroll
  for (int e = 0; e < NE; ++e){ a[e] = fabsf(emb[n * NE + e]); s += a[e]; }
  float inv = 1.0f / s;
  #pragma unroll
  for (int e = 0; e < NE; ++e) node_w[b * NE + e] = a[e] * inv;
}

// One block = (expert e, 64 batch rows). 512 threads = 8 waves.
// Register diet for 2 blocks/CU: U frags in regs (64); fx C-in and enc_W
// y-row live in LDS; acc processed sequentially per nf (16 regs).
__global__ __launch_bounds__(512, 4) void lstm_main(
    const float* __restrict__ y_prev,
    const float* __restrict__ enc_W,
    const float* __restrict__ enc_U,
    const float* __restrict__ dec_U,
    const float* __restrict__ out_w,
    const float* __restrict__ fxw_enc,
    const float* __restrict__ fxw_dec,
    float* __restrict__ ws_out)
{
  __shared__ unsigned short hl[2][BT * NH];  // 2 x 16 KB, XOR-swizzled rows
  __shared__ float fxl[2][NG];               // double-buffered fx (C-in), 4 KB
  __shared__ float w04_lds[NG];              // scaled enc_W y-row, 2 KB
  __shared__ float part[2][BT][9];           // decoder partials (+1 pad col)

  const int tid  = threadIdx.x;
  const int lane = tid & 63;
  const int w    = tid >> 6;
  const int e    = blockIdx.x & 7;
  const int b0   = (blockIdx.x >> 3) * BT;
  const int l15  = lane & 15;
  const int l4   = lane >> 4;              // 0..3
  const int hc0  = w * 16 + l4 * 4;        // thread's hidden-col base (rg adds 0..3)

  // precomputed swizzled LDS byte addresses (step-invariant)
  const int q   = (l15 >> 2) & 1;
  const int Ae  = l15 * 128 + ((l4 ^ (l15 & 3)) << 3);
  const int rb0 = 2 * (Ae + q * 32);
  const int rb1 = 2 * (Ae + (1 - q) * 32);
  const int wb  = 2 * ((l15 * 128 + hc0) ^ ((l15 & 7) << 3));

  const float* fxe = fxw_enc + e * NCONT * NG;
  const float* fxd0 = fxw_dec + e * NHOR * NG;

  { // init h buffer 0 = 0; stage w04 + fx(0)
    f32x4 z4 = {0.f, 0.f, 0.f, 0.f};
    ((f32x4*)&hl[0][0])[tid]       = z4;
    ((f32x4*)&hl[0][0])[tid + 512] = z4;
    float sc = ((tid >> 7) == 2) ? S_TANH : S_SIG;
    w04_lds[tid] = enc_W[(e * 9) * NG + tid] * sc;
    fxl[0][tid] = fxe[tid];
  }

  // A-frags: ut[g][kc], lane holds sc[g]*U[k = 32kc+8*l4+j][128g + w*16 + l15]
  bf16x8 ut[4][4];
  {
    const float* Ub = enc_U + e * NH * NG + w * 16 + l15;
    #pragma unroll
    for (int g = 0; g < 4; ++g){
      float scg = (g == 2) ? S_TANH : S_SIG;
      #pragma unroll
      for (int kc = 0; kc < 4; ++kc){
        const float* p = Ub + (kc * 32 + l4 * 8) * NG + g * NH;
        bf16x8 v;
        #pragma unroll
        for (int j = 0; j < 8; ++j) v[j] = (short)f2bf(p[j * NG] * scg);
        ut[g][kc] = v;
      }
    }
  }

  f32x2 cs2[4][2];   // scaled cell state c_s = 2log2e * c
  #pragma unroll
  for (int nf = 0; nf < 4; ++nf){ cs2[nf][0] = splat2(0.f); cs2[nf][1] = splat2(0.f); }

  f32x2 ow2[2];      // decoder out weights (set later)

  __syncthreads();

  // ---- one LSTM step. Reads h from hl[B], fx from fxl[B]; writes h to
  // hl[B^1]; stages next step's fx (fxn[tid]) into fxl[B^1]. ----
  auto step = [&](auto Bc, auto ENCc, const float* fxn, const float* ypt, float* pout){
    constexpr int  B   = decltype(Bc)::value;
    constexpr bool ENC = decltype(ENCc)::value;

    float fxst = fxn[tid];           // next-step fx, latency hidden under step
    float ycur[4];
    if constexpr (ENC){
      #pragma unroll
      for (int nf = 0; nf < 4; ++nf) ycur[nf] = ypt[nf * 16 + l15];
    }

    #pragma unroll
    for (int nf = 0; nf < 4; ++nf){
      bf16x8 hb[4];
      #pragma unroll
      for (int kc = 0; kc < 4; ++kc)
        hb[kc] = *(const bf16x8*)((const char*)hl +
                   (B * 16384 + nf * 4096 + (kc >> 1) * 128) + ((kc & 1) ? rb1 : rb0));
      f32x4 ag[4];
      #pragma unroll
      for (int g = 0; g < 4; ++g){
        f32x4 fxq = *(const f32x4*)&fxl[B][g * NH + hc0];   // LDS broadcast
        ag[g] = __builtin_amdgcn_mfma_f32_16x16x32_bf16(ut[g][0], hb[0], fxq, 0, 0, 0);
      }
      #pragma unroll
      for (int kc = 1; kc < 4; ++kc)
        #pragma unroll
        for (int g = 0; g < 4; ++g)
          ag[g] = __builtin_amdgcn_mfma_f32_16x16x32_bf16(ut[g][kc], hb[kc], ag[g], 0, 0, 0);

      // cell math
      f32x2 h2[2];
      f32x4 w0q[4];
      if constexpr (ENC){
        #pragma unroll
        for (int g = 0; g < 4; ++g) w0q[g] = *(const f32x4*)&w04_lds[g * NH + hc0];
      }
      #pragma unroll
      for (int hf = 0; hf < 2; ++hf){
        f32x2 zi = hf ? hi2(ag[0]) : lo2(ag[0]);
        f32x2 zf = hf ? hi2(ag[1]) : lo2(ag[1]);
        f32x2 zg = hf ? hi2(ag[2]) : lo2(ag[2]);
        f32x2 zo = hf ? hi2(ag[3]) : lo2(ag[3]);
        if constexpr (ENC){
          f32x2 y2 = splat2(ycur[nf]);
          zi = fma2(y2, hf ? hi2(w0q[0]) : lo2(w0q[0]), zi);
          zf = fma2(y2, hf ? hi2(w0q[1]) : lo2(w0q[1]), zf);
          zg = fma2(y2, hf ? hi2(w0q[2]) : lo2(w0q[2]), zg);
          zo = fma2(y2, hf ? hi2(w0q[3]) : lo2(w0q[3]), zo);
        }
        f32x2 gi = gate2(zi);                 // sigmoid(i)
        f32x2 gf = gate2(zf);                 // sigmoid(f)
        f32x2 go = gate2(zo);                 // sigmoid(o)
        f32x2 rg_ = gate2(zg);                // rcp(1+exp2(zg_s))
        f32x2 gg2 = fma2(rg_, splat2(-2.0f * S_TANH), splat2(S_TANH)); // 2log2e*tanh(g)
        f32x2 c  = fma2(gf, cs2[nf][hf], gi * gg2);   // scaled cell state
        cs2[nf][hf] = c;
        f32x2 rc = gate2(c);                  // rcp(1+exp2(c_s))
        f32x2 th = fma2(rc, splat2(-2.0f), splat2(1.0f));  // tanh(c)
        h2[hf] = go * th;
      }
      u32x2 pk;
      pk.x = cvt_pk_bf16(h2[0].x, h2[0].y);
      pk.y = cvt_pk_bf16(h2[1].x, h2[1].y);
      *(u32x2*)((char*)hl + ((B ^ 1) * 16384 + nf * 4096) + wb) = pk;
      if constexpr (!ENC){
        f32x2 pp = fma2(h2[0], ow2[0], h2[1] * ow2[1]);
        pout[nf] = pp.x + pp.y;
      }
    }
    fxl[B ^ 1][tid] = fxst;          // stage next fx (visible after barrier)
    __syncthreads();
  };

  // ---------------- encoder: 168 steps ----------------
  const float* ypt = y_prev + b0;
  for (int t = 0; t < NCONT; t += 2){
    step(ic<0>{}, std::true_type{}, fxe + NG, ypt, nullptr);
    ypt += NB;
    const float* nx = (t + 2 < NCONT) ? fxe + 2 * NG : fxd0;
    step(ic<1>{}, std::true_type{}, nx, ypt, nullptr);
    ypt += NB; fxe += 2 * NG;
  }

  // decoder A-frags (pre-scaled)
  {
    const float* Ub = dec_U + e * NH * NG + w * 16 + l15;
    #pragma unroll
    for (int g = 0; g < 4; ++g){
      float scg = (g == 2) ? S_TANH : S_SIG;
      #pragma unroll
      for (int kc = 0; kc < 4; ++kc){
        const float* p = Ub + (kc * 32 + l4 * 8) * NG + g * NH;
        bf16x8 v;
        #pragma unroll
        for (int j = 0; j < 8; ++j) v[j] = (short)f2bf(p[j * NG] * scg);
        ut[g][kc] = v;
      }
    }
  }
  {
    f32x4 ow4 = *(const f32x4*)&out_w[e * NH + hc0];
    ow2[0] = lo2(ow4); ow2[1] = hi2(ow4);
  }

  auto emit = [&](int t, float* pbuf){
    #pragma unroll
    for (int nf = 0; nf < 4; ++nf){
      pbuf[nf] += __shfl_xor(pbuf[nf], 16);
      pbuf[nf] += __shfl_xor(pbuf[nf], 32);
    }
    int pb = t & 1;
    if (lane < 16){
      #pragma unroll
      for (int nf = 0; nf < 4; ++nf) part[pb][nf * 16 + l15][w] = pbuf[nf];
    }
    __syncthreads();
    if (w == 0){
      float s = 0.f;
      #pragma unroll
      for (int ww = 0; ww < 8; ++ww) s += part[pb][lane][ww];
      ws_out[(e * NHOR + t) * NB + b0 + lane] = s;
    }
  };

  // ---------------- decoder: 24 steps ----------------
  const float* fxd = fxd0;
  #pragma unroll 1
  for (int td = 0; td < NHOR; td += 2){
    float pbuf[4];
    step(ic<0>{}, std::false_type{}, fxd + NG, nullptr, pbuf);
    emit(td, pbuf);
    const float* nx = (td + 2 < NHOR) ? fxd + 2 * NG : fxd + NG;
    step(ic<1>{}, std::false_type{}, nx, nullptr, pbuf);
    emit(td + 1, pbuf);
    fxd += 2 * NG;
  }
}

__global__ void finalize(const float* __restrict__ ws_out, const float* __restrict__ node_w,
                         float* __restrict__ out){
  int idx = blockIdx.x * blockDim.x + threadIdx.x;
  if (idx >= NHOR * NB) return;
  int b = idx & (NB - 1);
  float s = 0.f;
  #pragma unroll
  for (int e = 0; e < NE; ++e)
    s += ws_out[e * NHOR * NB + idx] * node_w[b * NE + e];
  out[idx] = s;
}

extern "C" void kernel_launch(void* const* d_in, const int* in_sizes, int n_in,
                              void* d_out, int out_size, void* d_ws, size_t ws_size,
                              hipStream_t stream) {
  const float* feats  = (const float*)d_in[0];
  const float* y_prev = (const float*)d_in[1];
  const int*   nid    = (const int*)  d_in[2];
  const float* emb    = (const float*)d_in[3];
  const float* enc_W  = (const float*)d_in[4];
  const float* enc_U  = (const float*)d_in[5];
  const float* enc_b  = (const float*)d_in[6];
  const float* dec_W  = (const float*)d_in[7];
  const float* dec_U  = (const float*)d_in[8];
  const float* dec_b  = (const float*)d_in[9];
  const float* out_w  = (const float*)d_in[10];
  float* out = (float*)d_out;

  float* ws      = (float*)d_ws;
  float* fxw_enc = ws;
  float* fxw_dec = fxw_enc + NE * NCONT * NG;
  float* node_w  = fxw_dec + NE * NHOR * NG;
  float* ws_out  = node_w + NB * NE;

  prep_fxw_enc<<<(NE * NCONT * NG + 255) / 256, 256, 0, stream>>>(feats, enc_W, enc_b, fxw_enc);
  prep_fxw_dec<<<(NE * NHOR * NG + 255) / 256, 256, 0, stream>>>(feats, dec_W, dec_b, fxw_dec);
  prep_node<<<(NB + 255) / 256, 256, 0, stream>>>(nid, emb, node_w);
  lstm_main<<<NE * (NB / BT), 512, 0, stream>>>(y_prev, enc_W, enc_U, dec_U, out_w,
                                                fxw_enc, fxw_dec, ws_out);
  finalize<<<(NHOR * NB + 255) / 256, 256, 0, stream>>>(ws_out, node_w, out);
}

// Round 11
// 1864.727 us; speedup vs baseline: 2.1720x; 2.1720x over previous
//
#include <hip/hip_runtime.h>
#include <stdint.h>
#include <type_traits>

#define NE 8
#define NH 128
#define ND 8
#define NCONT 168
#define NHOR 24
#define NB 4096
#define NG 512   // 4*NH
#define BT 32    // batch rows per block (32 -> fits 2 blocks/CU at <=128 regs)

// gate input scales folded into weights: i,f,o -> -log2(e); g -> +2*log2(e)
#define S_SIG (-1.44269504088896f)
#define S_TANH (2.88539008177793f)

typedef float f32x4 __attribute__((ext_vector_type(4)));
typedef float f32x2 __attribute__((ext_vector_type(2)));
typedef short bf16x8 __attribute__((ext_vector_type(8)));
typedef unsigned int u32x2 __attribute__((ext_vector_type(2)));

template <int N> using ic = std::integral_constant<int, N>;

__device__ __forceinline__ unsigned short f2bf(float f){
  union { float f; unsigned u; } v; v.f = f;
  unsigned r = (v.u + 0x7FFFu + ((v.u >> 16) & 1u)) >> 16;
  return (unsigned short)r;
}
__device__ __forceinline__ unsigned cvt_pk_bf16(float lo, float hi){
  unsigned r;
  asm("v_cvt_pk_bf16_f32 %0, %1, %2" : "=v"(r) : "v"(lo), "v"(hi));
  return r;
}

__device__ __forceinline__ f32x2 splat2(float v){ f32x2 r; r.x = v; r.y = v; return r; }
__device__ __forceinline__ f32x2 lo2(f32x4 v){ return __builtin_shufflevector(v, v, 0, 1); }
__device__ __forceinline__ f32x2 hi2(f32x4 v){ return __builtin_shufflevector(v, v, 2, 3); }
__device__ __forceinline__ f32x2 fma2(f32x2 a, f32x2 b, f32x2 c){
  return __builtin_elementwise_fma(a, b, c);
}
__device__ __forceinline__ f32x2 exp2_2(f32x2 x){
  f32x2 o; o.x = __builtin_amdgcn_exp2f(x.x); o.y = __builtin_amdgcn_exp2f(x.y); return o;
}
__device__ __forceinline__ f32x2 rcp2(f32x2 x){
  f32x2 o; o.x = __builtin_amdgcn_rcpf(x.x); o.y = __builtin_amdgcn_rcpf(x.y); return o;
}
// with z pre-scaled by -log2e: sigmoid = rcp(1 + exp2(z_s))
// with z pre-scaled by +2log2e: r = rcp(1+exp2(z_s)); tanh = 1 - 2r
__device__ __forceinline__ f32x2 gate2(f32x2 zs){
  return rcp2(exp2_2(zs) + splat2(1.0f));
}

__global__ void prep_fxw_enc(const float* __restrict__ feats, const float* __restrict__ W,
                             const float* __restrict__ bias, float* __restrict__ out){
  int idx = blockIdx.x * blockDim.x + threadIdx.x;
  if (idx >= NE * NCONT * NG) return;
  int j = idx & (NG - 1);
  int t = (idx >> 9) % NCONT;
  int e = idx / (NCONT * NG);
  float s = bias[e * NG + j];
  #pragma unroll
  for (int i = 0; i < ND; ++i)
    s += feats[t * ND + i] * W[(e * 9 + 1 + i) * NG + j];
  float sc = ((j >> 7) == 2) ? S_TANH : S_SIG;
  out[idx] = s * sc;
}

__global__ void prep_fxw_dec(const float* __restrict__ feats, const float* __restrict__ W,
                             const float* __restrict__ bias, float* __restrict__ out){
  int idx = blockIdx.x * blockDim.x + threadIdx.x;
  if (idx >= NE * NHOR * NG) return;
  int j = idx & (NG - 1);
  int t = (idx >> 9) % NHOR;
  int e = idx / (NHOR * NG);
  float s = bias[e * NG + j];
  #pragma unroll
  for (int i = 0; i < ND; ++i)
    s += feats[(NCONT + t) * ND + i] * W[(e * ND + i) * NG + j];
  float sc = ((j >> 7) == 2) ? S_TANH : S_SIG;
  out[idx] = s * sc;
}

__global__ void prep_node(const int* __restrict__ nid, const float* __restrict__ emb,
                          float* __restrict__ node_w){
  int b = blockIdx.x * blockDim.x + threadIdx.x;
  if (b >= NB) return;
  int n = nid[b];
  float a[NE]; float s = 0.f;
  #pragma unroll
  for (int e = 0; e < NE; ++e){ a[e] = fabsf(emb[n * NE + e]); s += a[e]; }
  float inv = 1.0f / s;
  #pragma unroll
  for (int e = 0; e < NE; ++e) node_w[b * NE + e] = a[e] * inv;
}

// One block = (expert e, 32 batch rows). 512 threads = 8 waves.
// Wave w owns hidden cols [w*16, w*16+16) for all 4 gates (U frags: 64 VGPR).
// BT=32 -> nf in {0,1}: total unified reg demand ~118 <= 128 -> 2 blocks/CU.
// Cross-block phase overlap replaces intra-block pipelining.
__global__ __launch_bounds__(512, 4) void lstm_main(
    const float* __restrict__ y_prev,
    const float* __restrict__ enc_W,
    const float* __restrict__ enc_U,
    const float* __restrict__ dec_U,
    const float* __restrict__ out_w,
    const float* __restrict__ fxw_enc,
    const float* __restrict__ fxw_dec,
    float* __restrict__ ws_out)
{
  __shared__ unsigned short hl[2][BT * NH];  // 2 x 8 KB, XOR-swizzled rows
  __shared__ float fxl[2][NG];               // double-buffered fx (C-in), 4 KB
  __shared__ float w04_lds[NG];              // scaled enc_W y-row, 2 KB
  __shared__ float part[2][BT][9];           // decoder partials (+1 pad col)

  const int tid  = threadIdx.x;
  const int lane = tid & 63;
  const int w    = tid >> 6;
  const int e    = blockIdx.x & 7;
  const int b0   = (blockIdx.x >> 3) * BT;
  const int l15  = lane & 15;
  const int l4   = lane >> 4;              // 0..3
  const int hc0  = w * 16 + l4 * 4;        // thread's hidden-col base (rg adds 0..3)

  // precomputed swizzled LDS byte addresses (step-invariant)
  const int q   = (l15 >> 2) & 1;
  const int Ae  = l15 * 128 + ((l4 ^ (l15 & 3)) << 3);
  const int rb0 = 2 * (Ae + q * 32);
  const int rb1 = 2 * (Ae + (1 - q) * 32);
  const int wb  = 2 * ((l15 * 128 + hc0) ^ ((l15 & 7) << 3));

  const float* fxe  = fxw_enc + e * NCONT * NG;
  const float* fxd0 = fxw_dec + e * NHOR * NG;

  { // init h buffer 0 = 0 (8 KB = 512 x 16 B); stage w04 + fx(0)
    f32x4 z4 = {0.f, 0.f, 0.f, 0.f};
    ((f32x4*)&hl[0][0])[tid] = z4;
    float sc = ((tid >> 7) == 2) ? S_TANH : S_SIG;
    w04_lds[tid] = enc_W[(e * 9) * NG + tid] * sc;
    fxl[0][tid] = fxe[tid];
  }

  // A-frags: ut[g][kc], lane holds sc[g]*U[k = 32kc+8*l4+j][128g + w*16 + l15]
  bf16x8 ut[4][4];
  {
    const float* Ub = enc_U + e * NH * NG + w * 16 + l15;
    #pragma unroll
    for (int g = 0; g < 4; ++g){
      float scg = (g == 2) ? S_TANH : S_SIG;
      #pragma unroll
      for (int kc = 0; kc < 4; ++kc){
        const float* p = Ub + (kc * 32 + l4 * 8) * NG + g * NH;
        bf16x8 v;
        #pragma unroll
        for (int j = 0; j < 8; ++j) v[j] = (short)f2bf(p[j * NG] * scg);
        ut[g][kc] = v;
      }
    }
  }

  f32x2 cs2[2][2];   // scaled cell state c_s = 2log2e * c
  #pragma unroll
  for (int nf = 0; nf < 2; ++nf){ cs2[nf][0] = splat2(0.f); cs2[nf][1] = splat2(0.f); }

  f32x2 ow2[2];      // decoder out weights (set later)

  __syncthreads();

  // ---- one LSTM step. h: hl[B] -> hl[B^1]; fx C-in from fxl[B]; stages
  // next step's fx into fxl[B^1]. ----
  auto step = [&](auto Bc, auto ENCc, const float* fxn, const float* ypt, float* pout){
    constexpr int  B   = decltype(Bc)::value;
    constexpr bool ENC = decltype(ENCc)::value;

    float fxst = fxn[tid];           // next-step fx, latency hidden under step
    float ycur[2];
    if constexpr (ENC){
      #pragma unroll
      for (int nf = 0; nf < 2; ++nf) ycur[nf] = ypt[nf * 16 + l15];
    }

    #pragma unroll
    for (int nf = 0; nf < 2; ++nf){
      bf16x8 hb[4];
      #pragma unroll
      for (int kc = 0; kc < 4; ++kc)
        hb[kc] = *(const bf16x8*)((const char*)hl +
                   (B * 8192 + nf * 4096 + (kc >> 1) * 128) + ((kc & 1) ? rb1 : rb0));
      f32x4 ag[4];
      #pragma unroll
      for (int g = 0; g < 4; ++g){
        f32x4 fxq = *(const f32x4*)&fxl[B][g * NH + hc0];   // LDS broadcast
        ag[g] = __builtin_amdgcn_mfma_f32_16x16x32_bf16(ut[g][0], hb[0], fxq, 0, 0, 0);
      }
      #pragma unroll
      for (int kc = 1; kc < 4; ++kc)
        #pragma unroll
        for (int g = 0; g < 4; ++g)
          ag[g] = __builtin_amdgcn_mfma_f32_16x16x32_bf16(ut[g][kc], hb[kc], ag[g], 0, 0, 0);

      // cell math
      f32x2 h2[2];
      #pragma unroll
      for (int hf = 0; hf < 2; ++hf){
        f32x2 zi = hf ? hi2(ag[0]) : lo2(ag[0]);
        f32x2 zf = hf ? hi2(ag[1]) : lo2(ag[1]);
        f32x2 zg = hf ? hi2(ag[2]) : lo2(ag[2]);
        f32x2 zo = hf ? hi2(ag[3]) : lo2(ag[3]);
        if constexpr (ENC){
          f32x2 y2 = splat2(ycur[nf]);
          zi = fma2(y2, *(const f32x2*)&w04_lds[0 * NH + hc0 + hf * 2], zi);
          zf = fma2(y2, *(const f32x2*)&w04_lds[1 * NH + hc0 + hf * 2], zf);
          zg = fma2(y2, *(const f32x2*)&w04_lds[2 * NH + hc0 + hf * 2], zg);
          zo = fma2(y2, *(const f32x2*)&w04_lds[3 * NH + hc0 + hf * 2], zo);
        }
        f32x2 gi = gate2(zi);                 // sigmoid(i)
        f32x2 gf = gate2(zf);                 // sigmoid(f)
        f32x2 go = gate2(zo);                 // sigmoid(o)
        f32x2 rg_ = gate2(zg);                // rcp(1+exp2(zg_s))
        f32x2 gg2 = fma2(rg_, splat2(-2.0f * S_TANH), splat2(S_TANH)); // 2log2e*tanh(g)
        f32x2 c  = fma2(gf, cs2[nf][hf], gi * gg2);   // scaled cell state
        cs2[nf][hf] = c;
        f32x2 rc = gate2(c);                  // rcp(1+exp2(c_s))
        f32x2 th = fma2(rc, splat2(-2.0f), splat2(1.0f));  // tanh(c)
        h2[hf] = go * th;
      }
      u32x2 pk;
      pk.x = cvt_pk_bf16(h2[0].x, h2[0].y);
      pk.y = cvt_pk_bf16(h2[1].x, h2[1].y);
      *(u32x2*)((char*)hl + ((B ^ 1) * 8192 + nf * 4096) + wb) = pk;
      if constexpr (!ENC){
        f32x2 pp = fma2(h2[0], ow2[0], h2[1] * ow2[1]);
        pout[nf] = pp.x + pp.y;
      }
    }
    fxl[B ^ 1][tid] = fxst;          // stage next fx (visible after barrier)
    __syncthreads();
  };

  // ---------------- encoder: 168 steps ----------------
  const float* ypt = y_prev + b0;
  for (int t = 0; t < NCONT; t += 2){
    step(ic<0>{}, std::true_type{}, fxe + NG, ypt, nullptr);
    ypt += NB;
    const float* nx = (t + 2 < NCONT) ? fxe + 2 * NG : fxd0;
    step(ic<1>{}, std::true_type{}, nx, ypt, nullptr);
    ypt += NB; fxe += 2 * NG;
  }

  // decoder A-frags (pre-scaled)
  {
    const float* Ub = dec_U + e * NH * NG + w * 16 + l15;
    #pragma unroll
    for (int g = 0; g < 4; ++g){
      float scg = (g == 2) ? S_TANH : S_SIG;
      #pragma unroll
      for (int kc = 0; kc < 4; ++kc){
        const float* p = Ub + (kc * 32 + l4 * 8) * NG + g * NH;
        bf16x8 v;
        #pragma unroll
        for (int j = 0; j < 8; ++j) v[j] = (short)f2bf(p[j * NG] * scg);
        ut[g][kc] = v;
      }
    }
  }
  {
    f32x4 ow4 = *(const f32x4*)&out_w[e * NH + hc0];
    ow2[0] = lo2(ow4); ow2[1] = hi2(ow4);
  }

  auto emit = [&](int t, float* pbuf){
    #pragma unroll
    for (int nf = 0; nf < 2; ++nf){
      pbuf[nf] += __shfl_xor(pbuf[nf], 16);
      pbuf[nf] += __shfl_xor(pbuf[nf], 32);
    }
    int pb = t & 1;
    if (lane < 16){
      #pragma unroll
      for (int nf = 0; nf < 2; ++nf) part[pb][nf * 16 + l15][w] = pbuf[nf];
    }
    __syncthreads();
    if (w == 0 && lane < BT){
      float s = 0.f;
      #pragma unroll
      for (int ww = 0; ww < 8; ++ww) s += part[pb][lane][ww];
      ws_out[(e * NHOR + t) * NB + b0 + lane] = s;
    }
  };

  // ---------------- decoder: 24 steps ----------------
  const float* fxd = fxd0;
  #pragma unroll 1
  for (int td = 0; td < NHOR; td += 2){
    float pbuf[2];
    step(ic<0>{}, std::false_type{}, fxd + NG, nullptr, pbuf);
    emit(td, pbuf);
    const float* nx = (td + 2 < NHOR) ? fxd + 2 * NG : fxd + NG;
    step(ic<1>{}, std::false_type{}, nx, nullptr, pbuf);
    emit(td + 1, pbuf);
    fxd += 2 * NG;
  }
}

__global__ void finalize(const float* __restrict__ ws_out, const float* __restrict__ node_w,
                         float* __restrict__ out){
  int idx = blockIdx.x * blockDim.x + threadIdx.x;
  if (idx >= NHOR * NB) return;
  int b = idx & (NB - 1);
  float s = 0.f;
  #pragma unroll
  for (int e = 0; e < NE; ++e)
    s += ws_out[e * NHOR * NB + idx] * node_w[b * NE + e];
  out[idx] = s;
}

extern "C" void kernel_launch(void* const* d_in, const int* in_sizes, int n_in,
                              void* d_out, int out_size, void* d_ws, size_t ws_size,
                              hipStream_t stream) {
  const float* feats  = (const float*)d_in[0];
  const float* y_prev = (const float*)d_in[1];
  const int*   nid    = (const int*)  d_in[2];
  const float* emb    = (const float*)d_in[3];
  const float* enc_W  = (const float*)d_in[4];
  const float* enc_U  = (const float*)d_in[5];
  const float* enc_b  = (const float*)d_in[6];
  const float* dec_W  = (const float*)d_in[7];
  const float* dec_U  = (const float*)d_in[8];
  const float* dec_b  = (const float*)d_in[9];
  const float* out_w  = (const float*)d_in[10];
  float* out = (float*)d_out;

  float* ws      = (float*)d_ws;
  float* fxw_enc = ws;
  float* fxw_dec = fxw_enc + NE * NCONT * NG;
  float* node_w  = fxw_dec + NE * NHOR * NG;
  float* ws_out  = node_w + NB * NE;

  prep_fxw_enc<<<(NE * NCONT * NG + 255) / 256, 256, 0, stream>>>(feats, enc_W, enc_b, fxw_enc);
  prep_fxw_dec<<<(NE * NHOR * NG + 255) / 256, 256, 0, stream>>>(feats, dec_W, dec_b, fxw_dec);
  prep_node<<<(NB + 255) / 256, 256, 0, stream>>>(nid, emb, node_w);
  lstm_main<<<NE * (NB / BT), 512, 0, stream>>>(y_prev, enc_W, enc_U, dec_U, out_w,
                                                fxw_enc, fxw_dec, ws_out);
  finalize<<<(NHOR * NB + 255) / 256, 256, 0, stream>>>(ws_out, node_w, out);
}